// Round 4
// baseline (366.407 us; speedup 1.0000x reference)
//
#include <hip/hip_runtime.h>
#include <math.h>

#define BATCH 8
#define SEQ   2048      // LQ == LK
#define DIM   1024      // DQ == DK == DV
#define TOPK  64
#define NEGMASK -1e30f
#define CAND_THRESH 16.0f   // drop alpha <= e^-16: g <= 1.1e-7, invisible at 2e-3
#define CAP 28              // candidate slots per [row][tile][half]

typedef _Float16 f16;
typedef _Float16 f16x8 __attribute__((ext_vector_type(8)));
typedef float f32x4 __attribute__((ext_vector_type(4)));

// async global->LDS, 16B per lane; LDS dest is wave-uniform base + lane*16.
__device__ __forceinline__ void async_load16(const void* g, void* l) {
  __builtin_amdgcn_global_load_lds(
      (const __attribute__((address_space(1))) void*)g,
      (__attribute__((address_space(3))) void*)l, 16, 0, 0);
}

// ---------------- mask pack: [16384][2048] i32 -> [16384][32] u64 bits ----------------
__global__ __launch_bounds__(256) void pack_mask_kernel(
    const int* __restrict__ mask, unsigned long long* __restrict__ mb) {
  const int wave = threadIdx.x >> 6, lane = threadIdx.x & 63;
  for (size_t w = blockIdx.x * 4 + wave; w < (size_t)16384 * 32; w += 2048 * 4) {
    int m = mask[w * 64 + lane];
    unsigned long long bits = __ballot(m != 0);
    if (lane == 0) mb[w] = bits;
  }
}

// ---------------- colsum of values over t, per (b, d) ----------------
__global__ __launch_bounds__(256) void colsum_partial_kernel(
    const float* __restrict__ values, float* __restrict__ partial) {
  int bid = blockIdx.x;          // 256 = tc(8) * b(8) * dg(4)
  int tc = bid >> 5;
  int b  = (bid >> 2) & 7;
  int dg = bid & 3;
  int d  = dg * 256 + threadIdx.x;
  const float* vp = values + ((size_t)b * SEQ + (size_t)tc * 256) * DIM + d;
  float s = 0.f;
  #pragma unroll 8
  for (int t = 0; t < 256; ++t) s += vp[(size_t)t * DIM];
  partial[((size_t)tc * BATCH + b) * DIM + d] = s;
}

__global__ __launch_bounds__(256) void colsum_reduce_kernel(
    const float* __restrict__ partial, float* __restrict__ colsum) {
  int idx = blockIdx.x * 256 + threadIdx.x;   // 8192 = 8*1024
  float s = 0.f;
  #pragma unroll
  for (int tc = 0; tc < 8; ++tc) s += partial[(size_t)tc * 8192 + idx];
  colsum[idx] = s;
}

// ---------------- f32 -> f16 conversion ----------------
__global__ __launch_bounds__(256) void cvt_f32_to_f16(
    const float* __restrict__ in, f16* __restrict__ out, int n) {
  int i = (blockIdx.x * 256 + threadIdx.x) * 4;
  if (i >= n) return;
  float4 v = *(const float4*)(in + i);
  union { f16 h[4]; uint2 u; } pk;
  pk.h[0] = (f16)v.x; pk.h[1] = (f16)v.y; pk.h[2] = (f16)v.z; pk.h[3] = (f16)v.w;
  *(uint2*)(out + i) = pk.u;
}

// ---------------- MFMA bt-GEMM core (m97 structure, fp16) ----------------
// C[128][128] per block = A-panel[128][K] . B-panel[128][K]^T, BK=32.
// LDS tile: [128 rows][4 slots of 8 f16], slot XOR-swizzled (rule #21:
// linear LDS dest via global_load_lds + inverse-swizzled global src +
// swizzled ds_read_b128) -> conflict-free fragment reads.

#define GEMM_PROLOGUE(APTR, BPTR)                                           \
  const int tid = threadIdx.x;                                              \
  const int wave = tid >> 6, lane = tid & 63;                               \
  const int wm = (wave >> 1) * 64, wn = (wave & 1) * 64;                    \
  const int r0 = wave * 32 + (lane >> 2);                                   \
  const int c16 = (lane & 3) ^ ((r0 >> 1) & 3);                            \
  const f16* srcA0 = (APTR) + (size_t)(m0 + r0) * DIM + c16 * 8;           \
  const f16* srcA1 = (APTR) + (size_t)(m0 + r0 + 16) * DIM + c16 * 8;      \
  const f16* srcB0 = (BPTR) + (size_t)(n0 + r0) * DIM + c16 * 8;           \
  const f16* srcB1 = (BPTR) + (size_t)(n0 + r0 + 16) * DIM + c16 * 8;      \
  char* ldsA0 = smA + wave * 2048;                                          \
  char* ldsA1 = smA + wave * 2048 + 1024;                                   \
  char* ldsB0 = smB + wave * 2048;                                          \
  char* ldsB1 = smB + wave * 2048 + 1024;                                   \
  int offA[4], offB[4];                                                     \
  _Pragma("unroll")                                                         \
  for (int i = 0; i < 4; ++i) {                                             \
    int r = wm + i * 16 + (lane & 15);                                      \
    offA[i] = r * 64 + ((lane >> 4) ^ ((r >> 1) & 3)) * 16;                 \
    int rn = wn + i * 16 + (lane & 15);                                     \
    offB[i] = rn * 64 + ((lane >> 4) ^ ((rn >> 1) & 3)) * 16;               \
  }                                                                         \
  f32x4 acc[4][4];                                                          \
  _Pragma("unroll")                                                         \
  for (int i = 0; i < 4; ++i)                                               \
    _Pragma("unroll")                                                       \
    for (int j = 0; j < 4; ++j)                                             \
      acc[i][j] = (f32x4){0.f, 0.f, 0.f, 0.f};                              \
  for (int k0 = 0; k0 < DIM; k0 += 32) {                                    \
    async_load16(srcA0 + k0, ldsA0);                                        \
    async_load16(srcA1 + k0, ldsA1);                                        \
    async_load16(srcB0 + k0, ldsB0);                                        \
    async_load16(srcB1 + k0, ldsB1);                                        \
    __syncthreads();                                                        \
    f16x8 af[4], bf[4];                                                     \
    _Pragma("unroll")                                                       \
    for (int i = 0; i < 4; ++i) {                                           \
      af[i] = *(const f16x8*)(smA + offA[i]);                               \
      bf[i] = *(const f16x8*)(smB + offB[i]);                               \
    }                                                                       \
    _Pragma("unroll")                                                       \
    for (int i = 0; i < 4; ++i)                                             \
      _Pragma("unroll")                                                     \
      for (int j = 0; j < 4; ++j)                                           \
        acc[i][j] = __builtin_amdgcn_mfma_f32_16x16x32_f16(                 \
            af[i], bf[j], acc[i][j], 0, 0, 0);                              \
    __syncthreads();                                                        \
  }

__global__ __launch_bounds__(256) void gemm_qproj(
    const f16* __restrict__ A, const f16* __restrict__ Bw,
    f16* __restrict__ C) {
  __shared__ __align__(128) char smA[8192];
  __shared__ __align__(128) char smB[8192];
  const int m0 = blockIdx.y * 128;
  const int n0 = blockIdx.x * 128;
  GEMM_PROLOGUE(A, Bw)
  // C/D layout (verified m89/m91): col = lane&15, row = (lane>>4)*4 + reg
  const int cr = m0 + wm + (lane >> 4) * 4;
  const int cc = n0 + wn + (lane & 15);
  #pragma unroll
  for (int i = 0; i < 4; ++i)
    #pragma unroll
    for (int j = 0; j < 4; ++j)
      #pragma unroll
      for (int reg = 0; reg < 4; ++reg)
        C[(size_t)(cr + i * 16 + reg) * DIM + cc + j * 16] = (f16)acc[i][j][reg];
}

// scores GEMM + fused mask + per-row tile-max + candidate emission.
// Emits, per [row][128-col tile][64-col half], the candidates
// {s > tilemax(row,128 cols) - 16} (superset of global {s > mv-16}),
// deterministically ordered by column. No scores materialization.
__global__ __launch_bounds__(256) void gemm_scores(
    const f16* __restrict__ QP, const f16* __restrict__ K16,
    const unsigned long long* __restrict__ maskbits,  // [16384][32]
    float2* __restrict__ cand,                        // [16384][32][CAP]
    int* __restrict__ counts) {                       // [16384][32]
  __shared__ __align__(128) char smA[8192];
  __shared__ __align__(128) char smB[8192];
  const int m0 = blockIdx.y * 128;     // global flat q-row (b*2048 + q)
  const int n0 = blockIdx.x * 128;     // t col within batch
  const int b  = m0 >> 11;
  const f16* Bk = K16 + (size_t)b * SEQ * DIM;
  GEMM_PROLOGUE(QP, Bk)

  const int g  = lane >> 4;    // 16-lane group = 4-row band
  const int lc = lane & 15;    // col within 16
  const int word = (n0 >> 6) + (wn >> 6);

  // apply mask bits into acc
  #pragma unroll
  for (int i = 0; i < 4; ++i)
    #pragma unroll
    for (int reg = 0; reg < 4; ++reg) {
      const int r = wm + i * 16 + g * 4 + reg;
      const unsigned long long mw = maskbits[(size_t)(m0 + r) * 32 + word];
      #pragma unroll
      for (int j = 0; j < 4; ++j)
        if (!((mw >> (lc + j * 16)) & 1ull)) acc[i][j][reg] = NEGMASK;
    }

  // per-row max over this wave's 64 cols -> LDS halfmax[128][2]
  float* hm = (float*)smA;   // 1 KB, LDS free after K-loop's final barrier
  #pragma unroll
  for (int i = 0; i < 4; ++i)
    #pragma unroll
    for (int reg = 0; reg < 4; ++reg) {
      const int r = wm + i * 16 + g * 4 + reg;
      float m4 = fmaxf(fmaxf(acc[i][0][reg], acc[i][1][reg]),
                       fmaxf(acc[i][2][reg], acc[i][3][reg]));
      #pragma unroll
      for (int off = 8; off >= 1; off >>= 1) m4 = fmaxf(m4, __shfl_xor(m4, off));
      if (lc == 0) hm[r * 2 + (wn >> 6)] = m4;
    }
  __syncthreads();

  // ballot-compact candidates (deterministic: slot = running popcount)
  const int pairbase = (n0 >> 7) * 2 + (wn >> 6);   // tile*2 + half
  #pragma unroll
  for (int i = 0; i < 4; ++i)
    #pragma unroll
    for (int reg = 0; reg < 4; ++reg) {
      const int r = wm + i * 16 + g * 4 + reg;
      const float tm = fmaxf(hm[r * 2], hm[r * 2 + 1]);
      const float thresh = fmaxf(tm - CAND_THRESH, -1e29f);
      float2* slot = cand + ((size_t)(m0 + r) * 32 + pairbase) * CAP;
      int cnt = 0;
      #pragma unroll
      for (int j = 0; j < 4; ++j) {
        const float s = acc[i][j][reg];
        const bool c = s > thresh;
        const unsigned long long bal = __ballot(c);
        const int seg = (int)((bal >> (g * 16)) & 0xFFFFull);
        const int pos = cnt + __popc(seg & ((1 << lc) - 1));
        if (c && pos < CAP) {
          float2 e; e.x = s; e.y = __int_as_float(n0 + wn + j * 16 + lc);
          slot[pos] = e;
        }
        cnt += __popc(seg);
      }
      if (lc == 0) counts[(size_t)(m0 + r) * 32 + pairbase] = cnt < CAP ? cnt : CAP;
    }
}

// ---------------- topk from candidate lists ----------------
// 1 wave per q-row; lane p<32 owns candidate group p=(tile*2+half).
// mv from all candidates; filter {s > mv-16}; Z from filtered (trunc err
// <= 2.3e-4 rel -> out err ~1e-6); gather V. F>64 -> exact serial top-64.
__global__ __launch_bounds__(512) void topk_kernel(
    const float2* __restrict__ cand,       // [16384][32][CAP]
    const int*    __restrict__ counts,     // [16384][32]
    const float*  __restrict__ values,     // [8][2048][1024]
    const float*  __restrict__ colsum,     // [8][1024]
    float* __restrict__ out)               // [16384][1024]
{
  __shared__ float ssc[8][128];
  __shared__ int   sidx[8][128];
  const int wave = threadIdx.x >> 6;
  const int lane = threadIdx.x & 63;
  const int grow = blockIdx.x * 8 + wave;      // global flat q-row
  const int b    = grow >> 11;
  float* msc = ssc[wave];
  int*   mix = sidx[wave];

  int cnt_p = 0;
  if (lane < 32) cnt_p = counts[(size_t)grow * 32 + lane];
  const float2* myslots = cand + ((size_t)grow * 32 + lane) * CAP;

  // pass 1: global row max over candidates
  float mv = -3e38f;
  for (int k = 0; k < cnt_p; ++k) mv = fmaxf(mv, myslots[k].x);
  #pragma unroll
  for (int off = 32; off > 0; off >>= 1) mv = fmaxf(mv, __shfl_xor(mv, off));
  const bool dead = (mv <= -1e29f);   // fully-masked row -> uniform softmax

  float total_g = 0.f;
  f32x4 oacc[4];
  #pragma unroll
  for (int j = 0; j < 4; ++j) oacc[j] = (f32x4){0.f, 0.f, 0.f, 0.f};
  const float* vbase = values + (size_t)b * SEQ * DIM;

  if (!dead) {
    const float thresh = mv - CAND_THRESH;
    // pass 2: filter count + Z partial
    int f = 0; float zp = 0.f;
    for (int k = 0; k < cnt_p; ++k) {
      float s = myslots[k].x;
      if (s > thresh) { ++f; zp += __expf(s - mv); }
    }
    // prefix over 64 lanes for deterministic compaction order
    int incl = f;
    #pragma unroll
    for (int off = 1; off < 64; off <<= 1) {
      int t = __shfl_up(incl, off);
      if (lane >= off) incl += t;
    }
    const int base = incl - f;
    const int F = __shfl(incl, 63);
    #pragma unroll
    for (int off = 32; off > 0; off >>= 1) zp += __shfl_xor(zp, off);
    const float Z = zp;
    // compact filtered candidates to LDS (order: (pair, slot))
    int w = 0;
    for (int k = 0; k < cnt_p; ++k) {
      float2 cv = myslots[k];
      if (cv.x > thresh) {
        int p = base + w;
        if (p < 128) { msc[p] = cv.x; mix[p] = __float_as_int(cv.y); }
        ++w;
      }
    }
    asm volatile("s_waitcnt lgkmcnt(0)" ::: "memory");

    if (F <= TOPK) {
      // common path: filtered set == significant top-k members
      for (int c = 0; c < F; ++c) {
        float g = expm1f(__expf(msc[c] - mv) / Z);
        total_g += g;
        const float* vrow = vbase + (size_t)mix[c] * DIM;
        #pragma unroll
        for (int j = 0; j < 4; ++j) {
          f32x4 v = *(const f32x4*)(vrow + j * 256 + lane * 4);
          #pragma unroll
          for (int e = 0; e < 4; ++e) oacc[j][e] = fmaf(g, v[e], oacc[j][e]);
        }
      }
    } else {
      // rare path: exact top-64 by (score desc, idx asc) from the list
      const int nlist = F < 128 ? F : 128;
      for (int itk = 0; itk < TOPK; ++itk) {
        float bv = -3e38f; int bi = 1 << 30; int bsl = -1;
        #pragma unroll
        for (int h = 0; h < 2; ++h) {
          int sl = lane + h * 64;
          if (sl < nlist) {
            float v = msc[sl]; int id = mix[sl];
            if (v > bv || (v == bv && id < bi)) { bv = v; bi = id; bsl = sl; }
          }
        }
        #pragma unroll
        for (int off = 32; off > 0; off >>= 1) {
          float ov = __shfl_xor(bv, off);
          int   oi = __shfl_xor(bi, off);
          int   os = __shfl_xor(bsl, off);
          if (ov > bv || (ov == bv && oi < bi)) { bv = ov; bi = oi; bsl = os; }
        }
        if (bv <= -1e29f) break;
        float g = expm1f(__expf(bv - mv) / Z);
        total_g += g;
        const float* vrow = vbase + (size_t)bi * DIM;
        #pragma unroll
        for (int j = 0; j < 4; ++j) {
          f32x4 v = *(const f32x4*)(vrow + j * 256 + lane * 4);
          #pragma unroll
          for (int e = 0; e < 4; ++e) oacc[j][e] = fmaf(g, v[e], oacc[j][e]);
        }
        if (lane == 0) msc[bsl] = -3e38f;
        asm volatile("s_waitcnt lgkmcnt(0)" ::: "memory");
      }
    }
  }

  // out = (colsum + sum g*v) / (2048 + sum g)
  const float inv = 1.0f / (2048.0f + total_g);
  const float* cs = colsum + (size_t)b * DIM;
  float* orow = out + (size_t)grow * DIM;
  #pragma unroll
  for (int j = 0; j < 4; ++j) {
    f32x4 c = *(const f32x4*)(cs + j * 256 + lane * 4);
    f32x4 o;
    #pragma unroll
    for (int e = 0; e < 4; ++e) o[e] = (c[e] + oacc[j][e]) * inv;
    *(f32x4*)(orow + j * 256 + lane * 4) = o;
  }
}

extern "C" void kernel_launch(void* const* d_in, const int* in_sizes, int n_in,
                              void* d_out, int out_size, void* d_ws, size_t ws_size,
                              hipStream_t stream) {
  const float* queries = (const float*)d_in[0];
  const float* keys    = (const float*)d_in[1];
  const float* values  = (const float*)d_in[2];
  const int*   mask    = (const int*)d_in[3];
  const float* W       = (const float*)d_in[4];
  float* out = (float*)d_out;

  // ws layout (bytes), total ~192.3 MB (same proven footprint):
  //   [0, 112M)    cand float2[16384][32][28]  (112 MB exactly)
  //       q16 aliases [0, 32M)   (dead before gemm_scores)
  //       w16 aliases [32M, 34M) (dead before gemm_scores)
  //   [112M, 114M) counts int[16384][32]
  //   [114M, 118M) maskbits u64[16384][32]
  //   [128M, 160M) qp16 f16 [16384][1024]
  //   [160M, 192M) k16  f16 [8][2048][1024]
  //   [192M, ...)  colsum f32 8192 | partial f32 65536
  char* base = (char*)d_ws;
  float2* cand   = (float2*)base;
  f16*   q16     = (f16*)base;
  f16*   w16     = (f16*)(base + (size_t)32 * 1024 * 1024);
  int*   counts  = (int*)(base + (size_t)112 * 1024 * 1024);
  unsigned long long* maskbits =
      (unsigned long long*)(base + (size_t)114 * 1024 * 1024);
  f16*   qp16    = (f16*)(base + (size_t)128 * 1024 * 1024);
  f16*   k16     = (f16*)(base + (size_t)160 * 1024 * 1024);
  float* colsum  = (float*)(base + (size_t)192 * 1024 * 1024);
  float* partial = colsum + 8192;

  pack_mask_kernel<<<2048, 256, 0, stream>>>(mask, maskbits);
  colsum_partial_kernel<<<256, 256, 0, stream>>>(values, partial);
  colsum_reduce_kernel<<<32, 256, 0, stream>>>(partial, colsum);
  cvt_f32_to_f16<<<16384, 256, 0, stream>>>(queries, q16, 16384 * 1024);
  cvt_f32_to_f16<<<1024, 256, 0, stream>>>(W, w16, 1024 * 1024);
  gemm_qproj<<<dim3(8, 128), 256, 0, stream>>>(q16, w16, qp16);
  cvt_f32_to_f16<<<16384, 256, 0, stream>>>(keys, k16, 16384 * 1024);
  gemm_scores<<<dim3(16, 128), 256, 0, stream>>>(qp16, k16, maskbits, cand, counts);
  topk_kernel<<<2048, 512, 0, stream>>>(cand, counts, values, colsum, out);
}

// Round 5
// 344.136 us; speedup vs baseline: 1.0647x; 1.0647x over previous
//
#include <hip/hip_runtime.h>
#include <math.h>

#define BATCH 8
#define SEQ   2048      // LQ == LK
#define DIM   1024      // DQ == DK == DV
#define TOPK  64
#define NEGMASK -1e30f
#define CAND_THRESH 16.0f   // drop alpha <= e^-16: g <= 1.1e-7, invisible at 2e-3
#define CAP 28              // candidate slots per [row][tile][half]

typedef _Float16 f16;
typedef _Float16 f16x8 __attribute__((ext_vector_type(8)));
typedef float f32x4 __attribute__((ext_vector_type(4)));

// async global->LDS, 16B per lane; LDS dest is wave-uniform base + lane*16.
__device__ __forceinline__ void async_load16(const void* g, void* l) {
  __builtin_amdgcn_global_load_lds(
      (const __attribute__((address_space(1))) void*)g,
      (__attribute__((address_space(3))) void*)l, 16, 0, 0);
}

// ---------------- mask pack ----------------
// Layout: word (grp*4 + j), bit l  <->  column grp*256 + 4*l + j.
// (int4 per lane -> 4 ballots; consumer arithmetic matches this bijection.)
__global__ __launch_bounds__(256) void pack_mask_kernel(
    const int4* __restrict__ mask4, unsigned long long* __restrict__ mb) {
  const int wave = threadIdx.x >> 6, lane = threadIdx.x & 63;
  const size_t nGrp = (size_t)16384 * 8;      // 256-col groups
  for (size_t g = blockIdx.x * 4 + wave; g < nGrp; g += 2048 * 4) {
    int4 v = mask4[g * 64 + lane];
    unsigned long long b0 = __ballot(v.x != 0);
    unsigned long long b1 = __ballot(v.y != 0);
    unsigned long long b2 = __ballot(v.z != 0);
    unsigned long long b3 = __ballot(v.w != 0);
    if (lane == 0) {
      mb[g * 4 + 0] = b0; mb[g * 4 + 1] = b1;
      mb[g * 4 + 2] = b2; mb[g * 4 + 3] = b3;
    }
  }
}

// ---------------- colsum of values over t, per (b, d) ----------------
__global__ __launch_bounds__(256) void colsum_partial_kernel(
    const float* __restrict__ values, float* __restrict__ partial) {
  int bid = blockIdx.x;          // 256 = tc(8) * b(8) * dg(4)
  int tc = bid >> 5;
  int b  = (bid >> 2) & 7;
  int dg = bid & 3;
  int d  = dg * 256 + threadIdx.x;
  const float* vp = values + ((size_t)b * SEQ + (size_t)tc * 256) * DIM + d;
  float s = 0.f;
  #pragma unroll 8
  for (int t = 0; t < 256; ++t) s += vp[(size_t)t * DIM];
  partial[((size_t)tc * BATCH + b) * DIM + d] = s;
}

__global__ __launch_bounds__(256) void colsum_reduce_kernel(
    const float* __restrict__ partial, float* __restrict__ colsum) {
  int idx = blockIdx.x * 256 + threadIdx.x;   // 8192 = 8*1024
  float s = 0.f;
  #pragma unroll
  for (int tc = 0; tc < 8; ++tc) s += partial[(size_t)tc * 8192 + idx];
  colsum[idx] = s;
}

// ---------------- f32 -> f16 conversion ----------------
__global__ __launch_bounds__(256) void cvt_f32_to_f16(
    const float* __restrict__ in, f16* __restrict__ out, int n) {
  int i = (blockIdx.x * 256 + threadIdx.x) * 4;
  if (i >= n) return;
  float4 v = *(const float4*)(in + i);
  union { f16 h[4]; uint2 u; } pk;
  pk.h[0] = (f16)v.x; pk.h[1] = (f16)v.y; pk.h[2] = (f16)v.z; pk.h[3] = (f16)v.w;
  *(uint2*)(out + i) = pk.u;
}

// ---------------- MFMA bt-GEMM core (fp16, 2-phase double-buffered) ----------------
// C[128][128] per block, BK=32, 256 thr. LDS: 2 buffers x (A 8KB + B 8KB).
// K-step: STAGE(next buf) -> ds_read frags(cur) -> MFMA -> barrier (drain
// lands AFTER compute -> loads overlap MFMA). Slot XOR-swizzle as before
// (rule #21: linear LDS dest, inverse-swizzled global src, swizzled read).

#define GEMM_PROLOGUE(APTR, BPTR)                                           \
  const int tid = threadIdx.x;                                              \
  const int wave = tid >> 6, lane = tid & 63;                               \
  const int wm = (wave >> 1) * 64, wn = (wave & 1) * 64;                    \
  const int r0 = wave * 32 + (lane >> 2);                                   \
  const int c16 = (lane & 3) ^ ((r0 >> 1) & 3);                            \
  const f16* srcA0 = (APTR) + (size_t)(m0 + r0) * DIM + c16 * 8;           \
  const f16* srcA1 = (APTR) + (size_t)(m0 + r0 + 16) * DIM + c16 * 8;      \
  const f16* srcB0 = (BPTR) + (size_t)(n0 + r0) * DIM + c16 * 8;           \
  const f16* srcB1 = (BPTR) + (size_t)(n0 + r0 + 16) * DIM + c16 * 8;      \
  int offA[4], offB[4];                                                     \
  _Pragma("unroll")                                                         \
  for (int i = 0; i < 4; ++i) {                                             \
    int r = wm + i * 16 + (lane & 15);                                      \
    offA[i] = r * 64 + ((lane >> 4) ^ ((r >> 1) & 3)) * 16;                 \
    int rn = wn + i * 16 + (lane & 15);                                     \
    offB[i] = rn * 64 + ((lane >> 4) ^ ((rn >> 1) & 3)) * 16;               \
  }                                                                         \
  f32x4 acc[4][4];                                                          \
  _Pragma("unroll")                                                         \
  for (int i = 0; i < 4; ++i)                                               \
    _Pragma("unroll")                                                       \
    for (int j = 0; j < 4; ++j)                                             \
      acc[i][j] = (f32x4){0.f, 0.f, 0.f, 0.f};                              \
  /* prologue: stage k0=0 into buffer 0 */                                  \
  async_load16(srcA0, smA + wave * 2048);                                   \
  async_load16(srcA1, smA + wave * 2048 + 1024);                            \
  async_load16(srcB0, smB + wave * 2048);                                   \
  async_load16(srcB1, smB + wave * 2048 + 1024);                            \
  __syncthreads();                                                          \
  int cur = 0;                                                              \
  for (int k0 = 0; k0 < DIM; k0 += 32) {                                    \
    const int nxt = cur ^ 1;                                                \
    if (k0 + 32 < DIM) {                                                    \
      async_load16(srcA0 + k0 + 32, smA + nxt * 8192 + wave * 2048);        \
      async_load16(srcA1 + k0 + 32, smA + nxt * 8192 + wave * 2048 + 1024); \
      async_load16(srcB0 + k0 + 32, smB + nxt * 8192 + wave * 2048);        \
      async_load16(srcB1 + k0 + 32, smB + nxt * 8192 + wave * 2048 + 1024); \
    }                                                                       \
    f16x8 af[4], bf[4];                                                     \
    _Pragma("unroll")                                                       \
    for (int i = 0; i < 4; ++i) {                                           \
      af[i] = *(const f16x8*)(smA + cur * 8192 + offA[i]);                  \
      bf[i] = *(const f16x8*)(smB + cur * 8192 + offB[i]);                  \
    }                                                                       \
    _Pragma("unroll")                                                       \
    for (int i = 0; i < 4; ++i)                                             \
      _Pragma("unroll")                                                     \
      for (int j = 0; j < 4; ++j)                                           \
        acc[i][j] = __builtin_amdgcn_mfma_f32_16x16x32_f16(                 \
            af[i], bf[j], acc[i][j], 0, 0, 0);                              \
    __syncthreads();  /* drains vmcnt AFTER MFMA; next stage overwrites cur */\
    cur = nxt;                                                              \
  }

__global__ __launch_bounds__(256) void gemm_qproj(
    const f16* __restrict__ A, const f16* __restrict__ Bw,
    f16* __restrict__ C) {
  __shared__ __align__(128) char smA[16384];
  __shared__ __align__(128) char smB[16384];
  // XCD-swizzled 1D grid: 1024 blocks, 8 n-tiles x 128 m-tiles
  const int swz = (blockIdx.x & 7) * 128 + (blockIdx.x >> 3);
  const int m0 = (swz >> 3) * 128;
  const int n0 = (swz & 7) * 128;
  GEMM_PROLOGUE(A, Bw)
  // C/D layout (verified m89/m91): col = lane&15, row = (lane>>4)*4 + reg
  const int cr = m0 + wm + (lane >> 4) * 4;
  const int cc = n0 + wn + (lane & 15);
  #pragma unroll
  for (int i = 0; i < 4; ++i)
    #pragma unroll
    for (int j = 0; j < 4; ++j)
      #pragma unroll
      for (int reg = 0; reg < 4; ++reg)
        C[(size_t)(cr + i * 16 + reg) * DIM + cc + j * 16] = (f16)acc[i][j][reg];
}

// scores GEMM + fused mask + per-row tile-max + candidate emission.
// Emits, per [row][128-col tile][64-col half], candidates
// {s > tilemax(row,128 cols) - 16} (superset of global {s > mv-16}).
__global__ __launch_bounds__(256) void gemm_scores(
    const f16* __restrict__ QP, const f16* __restrict__ K16,
    const unsigned long long* __restrict__ maskbits,  // [16384][8grp][4jw]
    float2* __restrict__ cand,                        // [16384][32][CAP]
    int* __restrict__ counts) {                       // [16384][32]
  __shared__ __align__(128) char smA[16384];
  __shared__ __align__(128) char smB[16384];
  // XCD-swizzled 1D grid: 2048 blocks; XCD x gets m-band = batch x.
  const int swz = (blockIdx.x & 7) * 256 + (blockIdx.x >> 3);
  const int m0 = (swz >> 4) * 128;     // global flat q-row tile
  const int n0 = (swz & 15) * 128;     // t col within batch
  const int b  = m0 >> 11;
  const f16* Bk = K16 + (size_t)b * SEQ * DIM;
  GEMM_PROLOGUE(QP, Bk)

  const int g  = lane >> 4;    // 16-lane group = 4-row band
  const int lc = lane & 15;    // col within 16

  // apply mask bits: word = grp*4 + (lc&3), bit = basebit + j*4 + (lc>>2)
  const int grp = (n0 + wn) >> 8;
  const int basebit = ((n0 + wn) & 255) >> 2;
  #pragma unroll
  for (int i = 0; i < 4; ++i)
    #pragma unroll
    for (int reg = 0; reg < 4; ++reg) {
      const int r = wm + i * 16 + g * 4 + reg;
      const unsigned long long mw =
          maskbits[(size_t)(m0 + r) * 32 + grp * 4 + (lc & 3)];
      #pragma unroll
      for (int j = 0; j < 4; ++j)
        if (!((mw >> (basebit + j * 4 + (lc >> 2))) & 1ull))
          acc[i][j][reg] = NEGMASK;
    }

  // per-row max over this wave's 64 cols -> LDS halfmax[128][2]
  float* hm = (float*)smA;   // LDS free after final K-loop barrier
  #pragma unroll
  for (int i = 0; i < 4; ++i)
    #pragma unroll
    for (int reg = 0; reg < 4; ++reg) {
      const int r = wm + i * 16 + g * 4 + reg;
      float m4 = fmaxf(fmaxf(acc[i][0][reg], acc[i][1][reg]),
                       fmaxf(acc[i][2][reg], acc[i][3][reg]));
      #pragma unroll
      for (int off = 8; off >= 1; off >>= 1) m4 = fmaxf(m4, __shfl_xor(m4, off));
      if (lc == 0) hm[r * 2 + (wn >> 6)] = m4;
    }
  __syncthreads();

  // ballot-compact candidates (deterministic: slot = running popcount)
  const int pairbase = (n0 >> 7) * 2 + (wn >> 6);   // tile*2 + half
  #pragma unroll
  for (int i = 0; i < 4; ++i)
    #pragma unroll
    for (int reg = 0; reg < 4; ++reg) {
      const int r = wm + i * 16 + g * 4 + reg;
      const float tm = fmaxf(hm[r * 2], hm[r * 2 + 1]);
      const float thresh = fmaxf(tm - CAND_THRESH, -1e29f);
      float2* slot = cand + ((size_t)(m0 + r) * 32 + pairbase) * CAP;
      int cnt = 0;
      #pragma unroll
      for (int j = 0; j < 4; ++j) {
        const float s = acc[i][j][reg];
        const bool c = s > thresh;
        const unsigned long long bal = __ballot(c);
        const int seg = (int)((bal >> (g * 16)) & 0xFFFFull);
        const int pos = cnt + __popc(seg & ((1 << lc) - 1));
        if (c && pos < CAP) {
          float2 e; e.x = s; e.y = __int_as_float(n0 + wn + j * 16 + lc);
          slot[pos] = e;
        }
        cnt += __popc(seg);
      }
      if (lc == 0) counts[(size_t)(m0 + r) * 32 + pairbase] = cnt < CAP ? cnt : CAP;
    }
}

// ---------------- topk from candidate lists ----------------
__global__ __launch_bounds__(512) void topk_kernel(
    const float2* __restrict__ cand,       // [16384][32][CAP]
    const int*    __restrict__ counts,     // [16384][32]
    const float*  __restrict__ values,     // [8][2048][1024]
    const float*  __restrict__ colsum,     // [8][1024]
    float* __restrict__ out)               // [16384][1024]
{
  __shared__ float ssc[8][128];
  __shared__ int   sidx[8][128];
  const int wave = threadIdx.x >> 6;
  const int lane = threadIdx.x & 63;
  const int grow = blockIdx.x * 8 + wave;      // global flat q-row
  const int b    = grow >> 11;
  float* msc = ssc[wave];
  int*   mix = sidx[wave];

  int cnt_p = 0;
  if (lane < 32) cnt_p = counts[(size_t)grow * 32 + lane];
  const float2* myslots = cand + ((size_t)grow * 32 + lane) * CAP;

  // pass 1: global row max over candidates
  float mv = -3e38f;
  for (int k = 0; k < cnt_p; ++k) mv = fmaxf(mv, myslots[k].x);
  #pragma unroll
  for (int off = 32; off > 0; off >>= 1) mv = fmaxf(mv, __shfl_xor(mv, off));
  const bool dead = (mv <= -1e29f);   // fully-masked row -> uniform softmax

  float total_g = 0.f;
  f32x4 oacc[4];
  #pragma unroll
  for (int j = 0; j < 4; ++j) oacc[j] = (f32x4){0.f, 0.f, 0.f, 0.f};
  const float* vbase = values + (size_t)b * SEQ * DIM;

  if (!dead) {
    const float thresh = mv - CAND_THRESH;
    // pass 2: filter count + Z partial
    int f = 0; float zp = 0.f;
    for (int k = 0; k < cnt_p; ++k) {
      float s = myslots[k].x;
      if (s > thresh) { ++f; zp += __expf(s - mv); }
    }
    // prefix over 64 lanes for deterministic compaction order
    int incl = f;
    #pragma unroll
    for (int off = 1; off < 64; off <<= 1) {
      int t = __shfl_up(incl, off);
      if (lane >= off) incl += t;
    }
    const int base = incl - f;
    const int F = __shfl(incl, 63);
    #pragma unroll
    for (int off = 32; off > 0; off >>= 1) zp += __shfl_xor(zp, off);
    const float Z = zp;
    // compact filtered candidates to LDS (order: (pair, slot))
    int w = 0;
    for (int k = 0; k < cnt_p; ++k) {
      float2 cv = myslots[k];
      if (cv.x > thresh) {
        int p = base + w;
        if (p < 128) { msc[p] = cv.x; mix[p] = __float_as_int(cv.y); }
        ++w;
      }
    }
    asm volatile("s_waitcnt lgkmcnt(0)" ::: "memory");

    if (F <= TOPK) {
      // common path: filtered set == significant top-k members
      for (int c = 0; c < F; ++c) {
        float g = expm1f(__expf(msc[c] - mv) / Z);
        total_g += g;
        const float* vrow = vbase + (size_t)mix[c] * DIM;
        #pragma unroll
        for (int j = 0; j < 4; ++j) {
          f32x4 v = *(const f32x4*)(vrow + j * 256 + lane * 4);
          #pragma unroll
          for (int e = 0; e < 4; ++e) oacc[j][e] = fmaf(g, v[e], oacc[j][e]);
        }
      }
    } else {
      // rare path: exact top-64 by (score desc, idx asc) from the list
      const int nlist = F < 128 ? F : 128;
      for (int itk = 0; itk < TOPK; ++itk) {
        float bv = -3e38f; int bi = 1 << 30; int bsl = -1;
        #pragma unroll
        for (int h = 0; h < 2; ++h) {
          int sl = lane + h * 64;
          if (sl < nlist) {
            float v = msc[sl]; int id = mix[sl];
            if (v > bv || (v == bv && id < bi)) { bv = v; bi = id; bsl = sl; }
          }
        }
        #pragma unroll
        for (int off = 32; off > 0; off >>= 1) {
          float ov = __shfl_xor(bv, off);
          int   oi = __shfl_xor(bi, off);
          int   os = __shfl_xor(bsl, off);
          if (ov > bv || (ov == bv && oi < bi)) { bv = ov; bi = oi; bsl = os; }
        }
        if (bv <= -1e29f) break;
        float g = expm1f(__expf(bv - mv) / Z);
        total_g += g;
        const float* vrow = vbase + (size_t)bi * DIM;
        #pragma unroll
        for (int j = 0; j < 4; ++j) {
          f32x4 v = *(const f32x4*)(vrow + j * 256 + lane * 4);
          #pragma unroll
          for (int e = 0; e < 4; ++e) oacc[j][e] = fmaf(g, v[e], oacc[j][e]);
        }
        if (lane == 0) msc[bsl] = -3e38f;
        asm volatile("s_waitcnt lgkmcnt(0)" ::: "memory");
      }
    }
  }

  // out = (colsum + sum g*v) / (2048 + sum g)
  const float inv = 1.0f / (2048.0f + total_g);
  const float* cs = colsum + (size_t)b * DIM;
  float* orow = out + (size_t)grow * DIM;
  #pragma unroll
  for (int j = 0; j < 4; ++j) {
    f32x4 c = *(const f32x4*)(cs + j * 256 + lane * 4);
    f32x4 o;
    #pragma unroll
    for (int e = 0; e < 4; ++e) o[e] = (c[e] + oacc[j][e]) * inv;
    *(f32x4*)(orow + j * 256 + lane * 4) = o;
  }
}

extern "C" void kernel_launch(void* const* d_in, const int* in_sizes, int n_in,
                              void* d_out, int out_size, void* d_ws, size_t ws_size,
                              hipStream_t stream) {
  const float* queries = (const float*)d_in[0];
  const float* keys    = (const float*)d_in[1];
  const float* values  = (const float*)d_in[2];
  const int*   mask    = (const int*)d_in[3];
  const float* W       = (const float*)d_in[4];
  float* out = (float*)d_out;

  // ws layout (bytes), total ~192.3 MB (same proven footprint):
  //   [0, 112M)    cand float2[16384][32][28]
  //       q16 aliases [0, 32M)   (dead before gemm_scores)
  //       w16 aliases [32M, 34M) (dead before gemm_scores)
  //   [112M, 114M) counts int[16384][32]
  //   [114M, 118M) maskbits u64[16384][32]
  //   [128M, 160M) qp16 f16 [16384][1024]
  //   [160M, 192M) k16  f16 [8][2048][1024]
  //   [192M, ...)  colsum f32 8192 | partial f32 65536
  char* base = (char*)d_ws;
  float2* cand   = (float2*)base;
  f16*   q16     = (f16*)base;
  f16*   w16     = (f16*)(base + (size_t)32 * 1024 * 1024);
  int*   counts  = (int*)(base + (size_t)112 * 1024 * 1024);
  unsigned long long* maskbits =
      (unsigned long long*)(base + (size_t)114 * 1024 * 1024);
  f16*   qp16    = (f16*)(base + (size_t)128 * 1024 * 1024);
  f16*   k16     = (f16*)(base + (size_t)160 * 1024 * 1024);
  float* colsum  = (float*)(base + (size_t)192 * 1024 * 1024);
  float* partial = colsum + 8192;

  pack_mask_kernel<<<2048, 256, 0, stream>>>((const int4*)mask, maskbits);
  colsum_partial_kernel<<<256, 256, 0, stream>>>(values, partial);
  colsum_reduce_kernel<<<32, 256, 0, stream>>>(partial, colsum);
  cvt_f32_to_f16<<<16384, 256, 0, stream>>>(queries, q16, 16384 * 1024);
  cvt_f32_to_f16<<<1024, 256, 0, stream>>>(W, w16, 1024 * 1024);
  gemm_qproj<<<1024, 256, 0, stream>>>(q16, w16, qp16);
  cvt_f32_to_f16<<<16384, 256, 0, stream>>>(keys, k16, 16384 * 1024);
  gemm_scores<<<2048, 256, 0, stream>>>(qp16, k16, maskbits, cand, counts);
  topk_kernel<<<2048, 512, 0, stream>>>(cand, counts, values, colsum, out);
}

// Round 6
// 318.935 us; speedup vs baseline: 1.1488x; 1.0790x over previous
//
#include <hip/hip_runtime.h>
#include <math.h>

#define BATCH 8
#define SEQ   2048      // LQ == LK
#define DIM   1024      // DQ == DK == DV
#define TOPK  64
#define NEGMASK -1e30f
#define CAND_THRESH 16.0f   // drop alpha <= e^-16: g <= 1.1e-7, invisible at 2e-3
#define CAP 28              // candidate slots per [row][64-col pair]
#define NK 16               // K-tiles of 64 (DIM/64)

typedef _Float16 f16;
typedef _Float16 f16x8 __attribute__((ext_vector_type(8)));
typedef float f32x4 __attribute__((ext_vector_type(4)));

// async global->LDS, 16B per lane; LDS dest is wave-uniform base + lane*16.
__device__ __forceinline__ void async_load16(const void* g, void* l) {
  __builtin_amdgcn_global_load_lds(
      (const __attribute__((address_space(1))) void*)g,
      (__attribute__((address_space(3))) void*)l, 16, 0, 0);
}

// ---------------- mask pack ----------------
// Layout: word (grp*4 + j), bit l  <->  column grp*256 + 4*l + j.
__global__ __launch_bounds__(256) void pack_mask_kernel(
    const int4* __restrict__ mask4, unsigned long long* __restrict__ mb) {
  const int wave = threadIdx.x >> 6, lane = threadIdx.x & 63;
  const size_t nGrp = (size_t)16384 * 8;      // 256-col groups
  for (size_t g = blockIdx.x * 4 + wave; g < nGrp; g += 2048 * 4) {
    int4 v = mask4[g * 64 + lane];
    unsigned long long b0 = __ballot(v.x != 0);
    unsigned long long b1 = __ballot(v.y != 0);
    unsigned long long b2 = __ballot(v.z != 0);
    unsigned long long b3 = __ballot(v.w != 0);
    if (lane == 0) {
      mb[g * 4 + 0] = b0; mb[g * 4 + 1] = b1;
      mb[g * 4 + 2] = b2; mb[g * 4 + 3] = b3;
    }
  }
}

// ---------------- colsum of values over t, per (b, d) ----------------
__global__ __launch_bounds__(256) void colsum_partial_kernel(
    const float* __restrict__ values, float* __restrict__ partial) {
  int bid = blockIdx.x;          // 256 = tc(8) * b(8) * dg(4)
  int tc = bid >> 5;
  int b  = (bid >> 2) & 7;
  int dg = bid & 3;
  int d  = dg * 256 + threadIdx.x;
  const float* vp = values + ((size_t)b * SEQ + (size_t)tc * 256) * DIM + d;
  float s = 0.f;
  #pragma unroll 8
  for (int t = 0; t < 256; ++t) s += vp[(size_t)t * DIM];
  partial[((size_t)tc * BATCH + b) * DIM + d] = s;
}

__global__ __launch_bounds__(256) void colsum_reduce_kernel(
    const float* __restrict__ partial, float* __restrict__ colsum) {
  int idx = blockIdx.x * 256 + threadIdx.x;   // 8192 = 8*1024
  float s = 0.f;
  #pragma unroll
  for (int tc = 0; tc < 8; ++tc) s += partial[(size_t)tc * 8192 + idx];
  colsum[idx] = s;
}

// ---------------- f32 -> f16 conversion ----------------
__global__ __launch_bounds__(256) void cvt_f32_to_f16(
    const float* __restrict__ in, f16* __restrict__ out, int n) {
  int i = (blockIdx.x * 256 + threadIdx.x) * 4;
  if (i >= n) return;
  float4 v = *(const float4*)(in + i);
  union { f16 h[4]; uint2 u; } pk;
  pk.h[0] = (f16)v.x; pk.h[1] = (f16)v.y; pk.h[2] = (f16)v.z; pk.h[3] = (f16)v.w;
  *(uint2*)(out + i) = pk.u;
}

// ================ 256x256 8-phase MFMA bt-GEMM core (T2+T3+T4+T5) ================
// 512 thr = 8 waves (2M x 4N); per-wave C = 128x64. BK=64, K-tile kt uses
// dbuf s=kt&1. LDS 128KB: A[s][h] at (s*2+h)*16384, B[s][h] at 65536+...
// Each 128x64 f16 half stored as rows of 8 16B-granules, granule XOR-swizzled
// by (row&7) (rule #21: linear LDS dest, inverse-swizzled global src,
// swizzled ds_read_b128 -> conflict-free; scheme bank-verified in r2-r5).
//
// Per K-tile: 4 phases. Phase p: ds_read A-frags fm{2p,2p+1} (+ all B frags
// at p0); stage ONE half-tile; s_barrier; lgkmcnt(0); setprio(1); 16 MFMA
// (quadrant); setprio(0); [p3: counted vmcnt]; s_barrier.
// Stage schedule (derived + in-flight-verified):
//   p0: A[kt+1][0]  p1: A[kt+1][1]  p2: B[kt+2][0]  p3: B[kt+2][1]
// p3 check vmcnt(4) retires B[kt+1] + A[kt+1] (needed at kt+1 p0), leaves
// B[kt+2] in flight (never drains to 0 until the tail, kt>=NK-2 -> vmcnt(0)).

#define STAGE2(PTR, SO, KT, H, REG0)                                         \
  {                                                                          \
    char* lb_ = sm + (REG0) + ((KT) & 1) * 32768 + (H) * 16384 + wave * 1024;\
    async_load16((PTR) + SO[H][0] + (KT) * 64, lb_);                         \
    async_load16((PTR) + SO[H][1] + (KT) * 64, lb_ + 8192);                  \
  }

#define GEMM256_CORE(APTR, BPTR)                                             \
  const int tid = threadIdx.x;                                               \
  const int wave = tid >> 6, lane = tid & 63;                                \
  const int lcq = lane >> 4, l15 = lane & 15;                                \
  const int pgk0 = (lcq ^ (lane & 7)) * 16;                                  \
  const int pgk1 = ((4 + lcq) ^ (lane & 7)) * 16;                            \
  const int aBase = (wave >> 2) * 16384 + l15 * 128;                         \
  const int bBase = 65536 + ((wave & 3) >> 1) * 16384 +                      \
                    ((wave & 1) * 64 + l15) * 128;                           \
  size_t soA[2][2], soB[2][2];                                               \
  _Pragma("unroll")                                                          \
  for (int h_ = 0; h_ < 2; ++h_)                                             \
    _Pragma("unroll")                                                        \
    for (int r_ = 0; r_ < 2; ++r_) {                                         \
      const int g_ = r_ * 512 + wave * 64 + lane;                            \
      const int lr_ = g_ >> 3;                                               \
      const int cg_ = (g_ & 7) ^ (lr_ & 7);                                  \
      soA[h_][r_] = (size_t)(m0 + h_ * 128 + lr_) * DIM + cg_ * 8;           \
      soB[h_][r_] = (size_t)(n0 + h_ * 128 + lr_) * DIM + cg_ * 8;           \
    }                                                                        \
  f32x4 acc[8][4];                                                           \
  _Pragma("unroll")                                                          \
  for (int i_ = 0; i_ < 8; ++i_)                                             \
    _Pragma("unroll")                                                        \
    for (int j_ = 0; j_ < 4; ++j_)                                           \
      acc[i_][j_] = (f32x4){0.f, 0.f, 0.f, 0.f};                             \
  STAGE2(BPTR, soB, 0, 0, 65536);                                            \
  STAGE2(BPTR, soB, 0, 1, 65536);                                            \
  STAGE2(APTR, soA, 0, 0, 0);                                                \
  STAGE2(APTR, soA, 0, 1, 0);                                                \
  STAGE2(BPTR, soB, 1, 0, 65536);                                            \
  STAGE2(BPTR, soB, 1, 1, 65536);                                            \
  asm volatile("s_waitcnt vmcnt(4)" ::: "memory");                           \
  __builtin_amdgcn_s_barrier();                                              \
  for (int kt = 0; kt < NK; ++kt) {                                          \
    const int sb = (kt & 1) * 32768;                                         \
    f16x8 bf[4][2];                                                          \
    _Pragma("unroll")                                                        \
    for (int p = 0; p < 4; ++p) {                                            \
      f16x8 a0 = *(const f16x8*)(sm + sb + aBase + (2*p) * 2048 + pgk0);     \
      f16x8 a1 = *(const f16x8*)(sm + sb + aBase + (2*p) * 2048 + pgk1);     \
      f16x8 a2 = *(const f16x8*)(sm + sb + aBase + (2*p+1) * 2048 + pgk0);   \
      f16x8 a3 = *(const f16x8*)(sm + sb + aBase + (2*p+1) * 2048 + pgk1);   \
      if (p == 0) {                                                          \
        _Pragma("unroll")                                                    \
        for (int fn = 0; fn < 4; ++fn) {                                     \
          bf[fn][0] = *(const f16x8*)(sm + sb + bBase + fn * 2048 + pgk0);   \
          bf[fn][1] = *(const f16x8*)(sm + sb + bBase + fn * 2048 + pgk1);   \
        }                                                                    \
        if (kt + 1 < NK) STAGE2(APTR, soA, kt + 1, 0, 0);                    \
      }                                                                      \
      if (p == 1 && kt + 1 < NK) STAGE2(APTR, soA, kt + 1, 1, 0);            \
      if (p == 2 && kt + 2 < NK) STAGE2(BPTR, soB, kt + 2, 0, 65536);        \
      if (p == 3 && kt + 2 < NK) STAGE2(BPTR, soB, kt + 2, 1, 65536);        \
      __builtin_amdgcn_s_barrier();                                          \
      asm volatile("s_waitcnt lgkmcnt(0)" ::: "memory");                     \
      __builtin_amdgcn_sched_barrier(0);                                     \
      __builtin_amdgcn_s_setprio(1);                                         \
      _Pragma("unroll")                                                      \
      for (int fn = 0; fn < 4; ++fn) {                                       \
        acc[2*p][fn]   = __builtin_amdgcn_mfma_f32_16x16x32_f16(             \
            a0, bf[fn][0], acc[2*p][fn], 0, 0, 0);                           \
        acc[2*p][fn]   = __builtin_amdgcn_mfma_f32_16x16x32_f16(             \
            a1, bf[fn][1], acc[2*p][fn], 0, 0, 0);                           \
        acc[2*p+1][fn] = __builtin_amdgcn_mfma_f32_16x16x32_f16(             \
            a2, bf[fn][0], acc[2*p+1][fn], 0, 0, 0);                         \
        acc[2*p+1][fn] = __builtin_amdgcn_mfma_f32_16x16x32_f16(             \
            a3, bf[fn][1], acc[2*p+1][fn], 0, 0, 0);                         \
      }                                                                      \
      __builtin_amdgcn_s_setprio(0);                                         \
      if (p == 3) {                                                          \
        if (kt + 2 < NK) { asm volatile("s_waitcnt vmcnt(4)" ::: "memory"); }\
        else             { asm volatile("s_waitcnt vmcnt(0)" ::: "memory"); }\
      }                                                                      \
      __builtin_amdgcn_s_barrier();                                          \
    }                                                                        \
  }

// C/D layout (verified r2+): within 16x16 frag, col = lane&15,
// row = (lane>>4)*4 + reg. Wave's C: rows (wave>>2)*128 + fm*16 + ...,
// cols (wave&3)*64 + fn*16 + ...

__global__ __launch_bounds__(512, 2) void gemm256_qproj(
    const f16* __restrict__ A, const f16* __restrict__ Bw,
    f16* __restrict__ C) {
  __shared__ __align__(128) char sm[131072];
  // XCD swizzle: 256 blocks, 64 m-tiles x 4 n-tiles; XCD x -> m-tiles 8x..8x+7
  const int swz = (blockIdx.x & 7) * 32 + (blockIdx.x >> 3);
  const int m0 = (swz >> 2) * 256;
  const int n0 = (swz & 3) * 256;
  GEMM256_CORE(A, Bw)
  #pragma unroll
  for (int fm = 0; fm < 8; ++fm)
    #pragma unroll
    for (int reg = 0; reg < 4; ++reg) {
      const int cr = m0 + (wave >> 2) * 128 + fm * 16 + lcq * 4 + reg;
      #pragma unroll
      for (int fn = 0; fn < 4; ++fn)
        C[(size_t)cr * DIM + n0 + (wave & 3) * 64 + fn * 16 + l15] =
            (f16)acc[fm][fn][reg];
    }
}

// scores GEMM + fused mask + 256-col tile-max + candidate emission.
// Emits per [row][64-col pair] the set {s > tilemax(row, 256 cols) - 16}
// (superset of global {s > mv-16} within those cols; tilemax <= mv).
__global__ __launch_bounds__(512, 2) void gemm256_scores(
    const f16* __restrict__ QP, const f16* __restrict__ K16,
    const unsigned long long* __restrict__ maskbits,  // [16384][32]
    float2* __restrict__ cand,                        // [16384][32][CAP]
    int* __restrict__ counts) {                       // [16384][32]
  __shared__ __align__(128) char sm[131072];
  // XCD swizzle: 512 blocks, 64 m-tiles x 8 n-tiles; XCD x -> batch x
  const int swz = (blockIdx.x & 7) * 64 + (blockIdx.x >> 3);
  const int m0 = (swz >> 3) * 256;     // global flat q-row tile base
  const int n0 = (swz & 7) * 256;      // t-col tile base (within batch)
  const int b  = m0 >> 11;
  const f16* Bk = K16 + (size_t)b * SEQ * DIM;
  GEMM256_CORE(QP, Bk)

  // ---- epilogue: mask, per-row 64-col max -> cross-wave 256-col max ----
  float* hmw = (float*)sm;   // [4 n-waves][256 rows]; LDS free after K-loop
  const int bbit = (wave & 3) * 16 + (l15 >> 2);
  const int mword = (n0 >> 8) * 4 + (l15 & 3);
  #pragma unroll
  for (int fm = 0; fm < 8; ++fm)
    #pragma unroll
    for (int reg = 0; reg < 4; ++reg) {
      const int lrow = (wave >> 2) * 128 + fm * 16 + lcq * 4 + reg;
      const unsigned long long mw = maskbits[(size_t)(m0 + lrow) * 32 + mword];
      #pragma unroll
      for (int fn = 0; fn < 4; ++fn)
        if (!((mw >> (bbit + fn * 4)) & 1ull)) acc[fm][fn][reg] = NEGMASK;
      float m4 = fmaxf(fmaxf(acc[fm][0][reg], acc[fm][1][reg]),
                       fmaxf(acc[fm][2][reg], acc[fm][3][reg]));
      #pragma unroll
      for (int off = 8; off >= 1; off >>= 1) m4 = fmaxf(m4, __shfl_xor(m4, off));
      if (l15 == 0) hmw[(wave & 3) * 256 + lrow] = m4;
    }
  __syncthreads();

  // ---- ballot-compact candidates (deterministic: slot = running popcount) ----
  const int pairb = (n0 >> 6) + (wave & 3);
  #pragma unroll
  for (int fm = 0; fm < 8; ++fm)
    #pragma unroll
    for (int reg = 0; reg < 4; ++reg) {
      const int lrow = (wave >> 2) * 128 + fm * 16 + lcq * 4 + reg;
      const size_t grow = (size_t)m0 + lrow;
      const float tm = fmaxf(fmaxf(hmw[lrow], hmw[256 + lrow]),
                             fmaxf(hmw[512 + lrow], hmw[768 + lrow]));
      const float thresh = fmaxf(tm - CAND_THRESH, -1e29f);
      float2* slot = cand + (grow * 32 + pairb) * CAP;
      int cnt = 0;
      #pragma unroll
      for (int fn = 0; fn < 4; ++fn) {
        const float s = acc[fm][fn][reg];
        const bool c = s > thresh;
        const unsigned long long bal = __ballot(c);
        const int seg = (int)((bal >> (lcq * 16)) & 0xFFFFull);
        const int pos = cnt + __popc(seg & ((1 << l15) - 1));
        if (c && pos < CAP) {
          float2 e;
          e.x = s;
          e.y = __int_as_float(n0 + (wave & 3) * 64 + fn * 16 + l15);
          slot[pos] = e;
        }
        cnt += __popc(seg);
      }
      if (l15 == 0) counts[grow * 32 + pairb] = cnt < CAP ? cnt : CAP;
    }
}

// ---------------- topk from candidate lists ----------------
__global__ __launch_bounds__(512) void topk_kernel(
    const float2* __restrict__ cand,       // [16384][32][CAP]
    const int*    __restrict__ counts,     // [16384][32]
    const float*  __restrict__ values,     // [8][2048][1024]
    const float*  __restrict__ colsum,     // [8][1024]
    float* __restrict__ out)               // [16384][1024]
{
  __shared__ float ssc[8][128];
  __shared__ int   sidx[8][128];
  const int wave = threadIdx.x >> 6;
  const int lane = threadIdx.x & 63;
  const int grow = blockIdx.x * 8 + wave;      // global flat q-row
  const int b    = grow >> 11;
  float* msc = ssc[wave];
  int*   mix = sidx[wave];

  int cnt_p = 0;
  if (lane < 32) cnt_p = counts[(size_t)grow * 32 + lane];
  const float2* myslots = cand + ((size_t)grow * 32 + lane) * CAP;

  // pass 1: global row max over candidates
  float mv = -3e38f;
  for (int k = 0; k < cnt_p; ++k) mv = fmaxf(mv, myslots[k].x);
  #pragma unroll
  for (int off = 32; off > 0; off >>= 1) mv = fmaxf(mv, __shfl_xor(mv, off));
  const bool dead = (mv <= -1e29f);   // fully-masked row -> uniform softmax

  float total_g = 0.f;
  f32x4 oacc[4];
  #pragma unroll
  for (int j = 0; j < 4; ++j) oacc[j] = (f32x4){0.f, 0.f, 0.f, 0.f};
  const float* vbase = values + (size_t)b * SEQ * DIM;

  if (!dead) {
    const float thresh = mv - CAND_THRESH;
    // pass 2: filter count + Z partial
    int f = 0; float zp = 0.f;
    for (int k = 0; k < cnt_p; ++k) {
      float s = myslots[k].x;
      if (s > thresh) { ++f; zp += __expf(s - mv); }
    }
    // prefix over 64 lanes for deterministic compaction order
    int incl = f;
    #pragma unroll
    for (int off = 1; off < 64; off <<= 1) {
      int t = __shfl_up(incl, off);
      if (lane >= off) incl += t;
    }
    const int base = incl - f;
    const int F = __shfl(incl, 63);
    #pragma unroll
    for (int off = 32; off > 0; off >>= 1) zp += __shfl_xor(zp, off);
    const float Z = zp;
    // compact filtered candidates to LDS (order: (pair, slot))
    int w = 0;
    for (int k = 0; k < cnt_p; ++k) {
      float2 cv = myslots[k];
      if (cv.x > thresh) {
        int p = base + w;
        if (p < 128) { msc[p] = cv.x; mix[p] = __float_as_int(cv.y); }
        ++w;
      }
    }
    asm volatile("s_waitcnt lgkmcnt(0)" ::: "memory");

    if (F <= TOPK) {
      // common path: filtered set == significant top-k members
      for (int c = 0; c < F; ++c) {
        float g = expm1f(__expf(msc[c] - mv) / Z);
        total_g += g;
        const float* vrow = vbase + (size_t)mix[c] * DIM;
        #pragma unroll
        for (int j = 0; j < 4; ++j) {
          f32x4 v = *(const f32x4*)(vrow + j * 256 + lane * 4);
          #pragma unroll
          for (int e = 0; e < 4; ++e) oacc[j][e] = fmaf(g, v[e], oacc[j][e]);
        }
      }
    } else {
      // rare path: exact top-64 by (score desc, idx asc) from the list
      const int nlist = F < 128 ? F : 128;
      for (int itk = 0; itk < TOPK; ++itk) {
        float bv = -3e38f; int bi = 1 << 30; int bsl = -1;
        #pragma unroll
        for (int h = 0; h < 2; ++h) {
          int sl = lane + h * 64;
          if (sl < nlist) {
            float v = msc[sl]; int id = mix[sl];
            if (v > bv || (v == bv && id < bi)) { bv = v; bi = id; bsl = sl; }
          }
        }
        #pragma unroll
        for (int off = 32; off > 0; off >>= 1) {
          float ov = __shfl_xor(bv, off);
          int   oi = __shfl_xor(bi, off);
          int   os = __shfl_xor(bsl, off);
          if (ov > bv || (ov == bv && oi < bi)) { bv = ov; bi = oi; bsl = os; }
        }
        if (bv <= -1e29f) break;
        float g = expm1f(__expf(bv - mv) / Z);
        total_g += g;
        const float* vrow = vbase + (size_t)bi * DIM;
        #pragma unroll
        for (int j = 0; j < 4; ++j) {
          f32x4 v = *(const f32x4*)(vrow + j * 256 + lane * 4);
          #pragma unroll
          for (int e = 0; e < 4; ++e) oacc[j][e] = fmaf(g, v[e], oacc[j][e]);
        }
        if (lane == 0) msc[bsl] = -3e38f;
        asm volatile("s_waitcnt lgkmcnt(0)" ::: "memory");
      }
    }
  }

  // out = (colsum + sum g*v) / (2048 + sum g)
  const float inv = 1.0f / (2048.0f + total_g);
  const float* cs = colsum + (size_t)b * DIM;
  float* orow = out + (size_t)grow * DIM;
  #pragma unroll
  for (int j = 0; j < 4; ++j) {
    f32x4 c = *(const f32x4*)(cs + j * 256 + lane * 4);
    f32x4 o;
    #pragma unroll
    for (int e = 0; e < 4; ++e) o[e] = (c[e] + oacc[j][e]) * inv;
    *(f32x4*)(orow + j * 256 + lane * 4) = o;
  }
}

extern "C" void kernel_launch(void* const* d_in, const int* in_sizes, int n_in,
                              void* d_out, int out_size, void* d_ws, size_t ws_size,
                              hipStream_t stream) {
  const float* queries = (const float*)d_in[0];
  const float* keys    = (const float*)d_in[1];
  const float* values  = (const float*)d_in[2];
  const int*   mask    = (const int*)d_in[3];
  const float* W       = (const float*)d_in[4];
  float* out = (float*)d_out;

  // ws layout (bytes), total ~192.3 MB (same proven footprint):
  //   [0, 112M)    cand float2[16384][32][28]
  //       q16 aliases [0, 32M)   (dead before gemm256_scores)
  //       w16 aliases [32M, 34M) (dead before gemm256_scores)
  //   [112M, 114M) counts int[16384][32]
  //   [114M, 118M) maskbits u64[16384][32]
  //   [128M, 160M) qp16 f16 [16384][1024]
  //   [160M, 192M) k16  f16 [8][2048][1024]
  //   [192M, ...)  colsum f32 8192 | partial f32 65536
  char* base = (char*)d_ws;
  float2* cand   = (float2*)base;
  f16*   q16     = (f16*)base;
  f16*   w16     = (f16*)(base + (size_t)32 * 1024 * 1024);
  int*   counts  = (int*)(base + (size_t)112 * 1024 * 1024);
  unsigned long long* maskbits =
      (unsigned long long*)(base + (size_t)114 * 1024 * 1024);
  f16*   qp16    = (f16*)(base + (size_t)128 * 1024 * 1024);
  f16*   k16     = (f16*)(base + (size_t)160 * 1024 * 1024);
  float* colsum  = (float*)(base + (size_t)192 * 1024 * 1024);
  float* partial = colsum + 8192;

  pack_mask_kernel<<<2048, 256, 0, stream>>>((const int4*)mask, maskbits);
  colsum_partial_kernel<<<256, 256, 0, stream>>>(values, partial);
  colsum_reduce_kernel<<<32, 256, 0, stream>>>(partial, colsum);
  cvt_f32_to_f16<<<16384, 256, 0, stream>>>(queries, q16, 16384 * 1024);
  cvt_f32_to_f16<<<1024, 256, 0, stream>>>(W, w16, 1024 * 1024);
  gemm256_qproj<<<256, 512, 0, stream>>>(q16, w16, qp16);
  cvt_f32_to_f16<<<16384, 256, 0, stream>>>(keys, k16, 16384 * 1024);
  gemm256_scores<<<512, 512, 0, stream>>>(qp16, k16, maskbits, cand, counts);
  topk_kernel<<<2048, 512, 0, stream>>>(cand, counts, values, colsum, out);
}

// Round 7
// 316.562 us; speedup vs baseline: 1.1575x; 1.0075x over previous
//
#include <hip/hip_runtime.h>
#include <math.h>

#define BATCH 8
#define SEQ   2048      // LQ == LK
#define DIM   1024      // DQ == DK == DV
#define TOPK  64
#define NEGMASK -1e30f
#define CAND_THRESH 16.0f   // drop alpha <= e^-16: g <= 1.1e-7, invisible at 2e-3
#define CAP 28              // candidate slots per [row][64-col pair]
#define NK 16               // K-tiles of 64 (DIM/64)

typedef _Float16 f16;
typedef _Float16 f16x8 __attribute__((ext_vector_type(8)));
typedef float f32x4 __attribute__((ext_vector_type(4)));

// async global->LDS, 16B per lane; LDS dest is wave-uniform base + lane*16.
__device__ __forceinline__ void async_load16(const void* g, void* l) {
  __builtin_amdgcn_global_load_lds(
      (const __attribute__((address_space(1))) void*)g,
      (__attribute__((address_space(3))) void*)l, 16, 0, 0);
}

// ---------------- mask pack ----------------
// Layout: word (grp*4 + j), bit l  <->  column grp*256 + 4*l + j.
// Two independent grp streams per wave per iter (halves serial latency depth).
__global__ __launch_bounds__(256) void pack_mask_kernel(
    const int4* __restrict__ mask4, unsigned long long* __restrict__ mb) {
  const int wave = threadIdx.x >> 6, lane = threadIdx.x & 63;
  const size_t nGrp = (size_t)16384 * 8;      // 256-col groups
  for (size_t g = (size_t)blockIdx.x * 8 + wave * 2; g < nGrp; g += 2048 * 8) {
    int4 v0 = mask4[g * 64 + lane];
    int4 v1 = mask4[(g + 1) * 64 + lane];
    unsigned long long a0 = __ballot(v0.x != 0);
    unsigned long long a1 = __ballot(v0.y != 0);
    unsigned long long a2 = __ballot(v0.z != 0);
    unsigned long long a3 = __ballot(v0.w != 0);
    unsigned long long b0 = __ballot(v1.x != 0);
    unsigned long long b1 = __ballot(v1.y != 0);
    unsigned long long b2 = __ballot(v1.z != 0);
    unsigned long long b3 = __ballot(v1.w != 0);
    if (lane == 0) {
      mb[g * 4 + 0] = a0; mb[g * 4 + 1] = a1;
      mb[g * 4 + 2] = a2; mb[g * 4 + 3] = a3;
      mb[g * 4 + 4] = b0; mb[g * 4 + 5] = b1;
      mb[g * 4 + 6] = b2; mb[g * 4 + 7] = b3;
    }
  }
}

// ---------------- colsum of values over t, per (b, d) ----------------
__global__ __launch_bounds__(256) void colsum_partial_kernel(
    const float* __restrict__ values, float* __restrict__ partial) {
  int bid = blockIdx.x;          // 256 = tc(8) * b(8) * dg(4)
  int tc = bid >> 5;
  int b  = (bid >> 2) & 7;
  int dg = bid & 3;
  int d  = dg * 256 + threadIdx.x;
  const float* vp = values + ((size_t)b * SEQ + (size_t)tc * 256) * DIM + d;
  float s = 0.f;
  #pragma unroll 8
  for (int t = 0; t < 256; ++t) s += vp[(size_t)t * DIM];
  partial[((size_t)tc * BATCH + b) * DIM + d] = s;
}

__global__ __launch_bounds__(256) void colsum_reduce_kernel(
    const float* __restrict__ partial, float* __restrict__ colsum) {
  int idx = blockIdx.x * 256 + threadIdx.x;   // 8192 = 8*1024
  float s = 0.f;
  #pragma unroll
  for (int tc = 0; tc < 8; ++tc) s += partial[(size_t)tc * 8192 + idx];
  colsum[idx] = s;
}

// ---------------- f32 -> f16 conversion ----------------
__global__ __launch_bounds__(256) void cvt_f32_to_f16(
    const float* __restrict__ in, f16* __restrict__ out, int n) {
  int i = (blockIdx.x * 256 + threadIdx.x) * 4;
  if (i >= n) return;
  float4 v = *(const float4*)(in + i);
  union { f16 h[4]; uint2 u; } pk;
  pk.h[0] = (f16)v.x; pk.h[1] = (f16)v.y; pk.h[2] = (f16)v.z; pk.h[3] = (f16)v.w;
  *(uint2*)(out + i) = pk.u;
}

// ================ 256x256 8-phase MFMA bt-GEMM core (T2+T3+T4+T5) ================
// 512 thr = 8 waves (2M x 4N); per-wave C = 128x64. BK=64, K-tile kt uses
// dbuf s=kt&1. LDS 128KB. Granule XOR-swizzle by (row&7) (rule #21: linear
// LDS dest via global_load_lds, inverse-swizzled global src, swizzled
// ds_read_b128 -> conflict-free; SQ_LDS_BANK_CONFLICT==0 verified r6).
//
// Fencing = EXACTLY the proven m201 set: raw s_barrier pairs, plain
// lgkmcnt(0) (no "memory" clobber), counted vmcnt once per K-tile
// (memory-clobbered), setprio around MFMA cluster. NO sched_barrier(0)
// (m141: order-pinning -> 510 TF; r6 measured 520 TF with it present).
//
// Stage schedule (in-flight-verified, r6, absmax-clean):
//   p0: A[kt+1][0]  p1: A[kt+1][1]  p2: B[kt+2][0]  p3: B[kt+2][1]
// p3 vmcnt(4) retires B[kt+1]+A[kt+1] (needed at kt+1 p0), leaves B[kt+2]
// in flight; tail (kt+2>=NK) drains with vmcnt(0).

#define STAGE2(PTR, SO, KT, H, REG0)                                         \
  {                                                                          \
    char* lb_ = sm + (REG0) + ((KT) & 1) * 32768 + (H) * 16384 + wave * 1024;\
    async_load16((PTR) + SO[H][0] + (KT) * 64, lb_);                         \
    async_load16((PTR) + SO[H][1] + (KT) * 64, lb_ + 8192);                  \
  }

#define GEMM256_CORE(APTR, BPTR)                                             \
  const int tid = threadIdx.x;                                               \
  const int wave = tid >> 6, lane = tid & 63;                                \
  const int lcq = lane >> 4, l15 = lane & 15;                                \
  const int pgk0 = (lcq ^ (lane & 7)) * 16;                                  \
  const int pgk1 = ((4 + lcq) ^ (lane & 7)) * 16;                            \
  const int aBase = (wave >> 2) * 16384 + l15 * 128;                         \
  const int bBase = 65536 + ((wave & 3) >> 1) * 16384 +                      \
                    ((wave & 1) * 64 + l15) * 128;                           \
  size_t soA[2][2], soB[2][2];                                               \
  _Pragma("unroll")                                                          \
  for (int h_ = 0; h_ < 2; ++h_)                                             \
    _Pragma("unroll")                                                        \
    for (int r_ = 0; r_ < 2; ++r_) {                                         \
      const int g_ = r_ * 512 + wave * 64 + lane;                            \
      const int lr_ = g_ >> 3;                                               \
      const int cg_ = (g_ & 7) ^ (lr_ & 7);                                  \
      soA[h_][r_] = (size_t)(m0 + h_ * 128 + lr_) * DIM + cg_ * 8;           \
      soB[h_][r_] = (size_t)(n0 + h_ * 128 + lr_) * DIM + cg_ * 8;           \
    }                                                                        \
  f32x4 acc[8][4];                                                           \
  _Pragma("unroll")                                                          \
  for (int i_ = 0; i_ < 8; ++i_)                                             \
    _Pragma("unroll")                                                        \
    for (int j_ = 0; j_ < 4; ++j_)                                           \
      acc[i_][j_] = (f32x4){0.f, 0.f, 0.f, 0.f};                             \
  STAGE2(BPTR, soB, 0, 0, 65536);                                            \
  STAGE2(BPTR, soB, 0, 1, 65536);                                            \
  STAGE2(APTR, soA, 0, 0, 0);                                                \
  STAGE2(APTR, soA, 0, 1, 0);                                                \
  STAGE2(BPTR, soB, 1, 0, 65536);                                            \
  STAGE2(BPTR, soB, 1, 1, 65536);                                            \
  asm volatile("s_waitcnt vmcnt(4)" ::: "memory");                           \
  __builtin_amdgcn_s_barrier();                                              \
  for (int kt = 0; kt < NK; ++kt) {                                          \
    const int sb = (kt & 1) * 32768;                                         \
    f16x8 bf[4][2];                                                          \
    _Pragma("unroll")                                                        \
    for (int p = 0; p < 4; ++p) {                                            \
      f16x8 a0 = *(const f16x8*)(sm + sb + aBase + (2*p) * 2048 + pgk0);     \
      f16x8 a1 = *(const f16x8*)(sm + sb + aBase + (2*p) * 2048 + pgk1);     \
      f16x8 a2 = *(const f16x8*)(sm + sb + aBase + (2*p+1) * 2048 + pgk0);   \
      f16x8 a3 = *(const f16x8*)(sm + sb + aBase + (2*p+1) * 2048 + pgk1);   \
      if (p == 0) {                                                          \
        _Pragma("unroll")                                                    \
        for (int fn = 0; fn < 4; ++fn) {                                     \
          bf[fn][0] = *(const f16x8*)(sm + sb + bBase + fn * 2048 + pgk0);   \
          bf[fn][1] = *(const f16x8*)(sm + sb + bBase + fn * 2048 + pgk1);   \
        }                                                                    \
        if (kt + 1 < NK) STAGE2(APTR, soA, kt + 1, 0, 0);                    \
      }                                                                      \
      if (p == 1 && kt + 1 < NK) STAGE2(APTR, soA, kt + 1, 1, 0);            \
      if (p == 2 && kt + 2 < NK) STAGE2(BPTR, soB, kt + 2, 0, 65536);        \
      if (p == 3 && kt + 2 < NK) STAGE2(BPTR, soB, kt + 2, 1, 65536);        \
      __builtin_amdgcn_s_barrier();                                          \
      asm volatile("s_waitcnt lgkmcnt(0)");                                  \
      __builtin_amdgcn_s_setprio(1);                                         \
      _Pragma("unroll")                                                      \
      for (int fn = 0; fn < 4; ++fn) {  /* 8 independent */                  \
        acc[2*p][fn]   = __builtin_amdgcn_mfma_f32_16x16x32_f16(             \
            a0, bf[fn][0], acc[2*p][fn], 0, 0, 0);                           \
        acc[2*p+1][fn] = __builtin_amdgcn_mfma_f32_16x16x32_f16(             \
            a2, bf[fn][0], acc[2*p+1][fn], 0, 0, 0);                         \
      }                                                                      \
      _Pragma("unroll")                                                      \
      for (int fn = 0; fn < 4; ++fn) {  /* 8 dependent on first 8 */         \
        acc[2*p][fn]   = __builtin_amdgcn_mfma_f32_16x16x32_f16(             \
            a1, bf[fn][1], acc[2*p][fn], 0, 0, 0);                           \
        acc[2*p+1][fn] = __builtin_amdgcn_mfma_f32_16x16x32_f16(             \
            a3, bf[fn][1], acc[2*p+1][fn], 0, 0, 0);                         \
      }                                                                      \
      __builtin_amdgcn_s_setprio(0);                                         \
      if (p == 3) {                                                          \
        if (kt + 2 < NK) { asm volatile("s_waitcnt vmcnt(4)" ::: "memory"); }\
        else             { asm volatile("s_waitcnt vmcnt(0)" ::: "memory"); }\
      }                                                                      \
      __builtin_amdgcn_s_barrier();                                          \
    }                                                                        \
  }

// C/D layout (verified r2+): within 16x16 frag, col = lane&15,
// row = (lane>>4)*4 + reg. Wave's C: rows (wave>>2)*128 + fm*16 + ...,
// cols (wave&3)*64 + fn*16 + ...

__global__ __launch_bounds__(512, 2) void gemm256_qproj(
    const f16* __restrict__ A, const f16* __restrict__ Bw,
    f16* __restrict__ C) {
  __shared__ __align__(128) char sm[131072];
  // XCD swizzle: 256 blocks, 64 m-tiles x 4 n-tiles
  const int swz = (blockIdx.x & 7) * 32 + (blockIdx.x >> 3);
  const int m0 = (swz >> 2) * 256;
  const int n0 = (swz & 3) * 256;
  GEMM256_CORE(A, Bw)
  #pragma unroll
  for (int fm = 0; fm < 8; ++fm)
    #pragma unroll
    for (int reg = 0; reg < 4; ++reg) {
      const int cr = m0 + (wave >> 2) * 128 + fm * 16 + lcq * 4 + reg;
      #pragma unroll
      for (int fn = 0; fn < 4; ++fn)
        C[(size_t)cr * DIM + n0 + (wave & 3) * 64 + fn * 16 + l15] =
            (f16)acc[fm][fn][reg];
    }
}

// scores GEMM + fused mask + 256-col tile-max + candidate emission.
// Emits per [row][64-col pair] the set {s > tilemax(row, 256 cols) - 16}
// (superset of global {s > mv-16} within those cols; tilemax <= mv).
__global__ __launch_bounds__(512, 2) void gemm256_scores(
    const f16* __restrict__ QP, const f16* __restrict__ K16,
    const unsigned long long* __restrict__ maskbits,  // [16384][32]
    float2* __restrict__ cand,                        // [16384][32][CAP]
    int* __restrict__ counts) {                       // [16384][32]
  __shared__ __align__(128) char sm[131072];
  // XCD swizzle: 512 blocks; XCD x -> batch x (K/QP panels L2-local)
  const int swz = (blockIdx.x & 7) * 64 + (blockIdx.x >> 3);
  const int m0 = (swz >> 3) * 256;     // global flat q-row tile base
  const int n0 = (swz & 7) * 256;      // t-col tile base (within batch)
  const int b  = m0 >> 11;
  const f16* Bk = K16 + (size_t)b * SEQ * DIM;
  GEMM256_CORE(QP, Bk)

  // ---- epilogue: mask, per-row 64-col max -> cross-wave 256-col max ----
  float* hmw = (float*)sm;   // [4 n-waves][256 rows]; LDS free after K-loop
  const int bbit = (wave & 3) * 16 + (l15 >> 2);
  const int mword = (n0 >> 8) * 4 + (l15 & 3);
  #pragma unroll
  for (int fm = 0; fm < 8; ++fm)
    #pragma unroll
    for (int reg = 0; reg < 4; ++reg) {
      const int lrow = (wave >> 2) * 128 + fm * 16 + lcq * 4 + reg;
      const unsigned long long mw = maskbits[(size_t)(m0 + lrow) * 32 + mword];
      #pragma unroll
      for (int fn = 0; fn < 4; ++fn)
        if (!((mw >> (bbit + fn * 4)) & 1ull)) acc[fm][fn][reg] = NEGMASK;
      float m4 = fmaxf(fmaxf(acc[fm][0][reg], acc[fm][1][reg]),
                       fmaxf(acc[fm][2][reg], acc[fm][3][reg]));
      #pragma unroll
      for (int off = 8; off >= 1; off >>= 1) m4 = fmaxf(m4, __shfl_xor(m4, off));
      if (l15 == 0) hmw[(wave & 3) * 256 + lrow] = m4;
    }
  __syncthreads();

  // ---- ballot-compact candidates (deterministic: slot = running popcount) ----
  const int pairb = (n0 >> 6) + (wave & 3);
  #pragma unroll
  for (int fm = 0; fm < 8; ++fm)
    #pragma unroll
    for (int reg = 0; reg < 4; ++reg) {
      const int lrow = (wave >> 2) * 128 + fm * 16 + lcq * 4 + reg;
      const size_t grow = (size_t)m0 + lrow;
      const float tm = fmaxf(fmaxf(hmw[lrow], hmw[256 + lrow]),
                             fmaxf(hmw[512 + lrow], hmw[768 + lrow]));
      const float thresh = fmaxf(tm - CAND_THRESH, -1e29f);
      float2* slot = cand + (grow * 32 + pairb) * CAP;
      int cnt = 0;
      #pragma unroll
      for (int fn = 0; fn < 4; ++fn) {
        const float s = acc[fm][fn][reg];
        const bool c = s > thresh;
        const unsigned long long bal = __ballot(c);
        const int seg = (int)((bal >> (lcq * 16)) & 0xFFFFull);
        const int pos = cnt + __popc(seg & ((1 << l15) - 1));
        if (c && pos < CAP) {
          float2 e;
          e.x = s;
          e.y = __int_as_float(n0 + (wave & 3) * 64 + fn * 16 + l15);
          slot[pos] = e;
        }
        cnt += __popc(seg);
      }
      if (l15 == 0) counts[grow * 32 + pairb] = cnt < CAP ? cnt : CAP;
    }
}

// ---------------- topk from candidate lists ----------------
__global__ __launch_bounds__(512) void topk_kernel(
    const float2* __restrict__ cand,       // [16384][32][CAP]
    const int*    __restrict__ counts,     // [16384][32]
    const float*  __restrict__ values,     // [8][2048][1024]
    const float*  __restrict__ colsum,     // [8][1024]
    float* __restrict__ out)               // [16384][1024]
{
  __shared__ float ssc[8][128];
  __shared__ int   sidx[8][128];
  const int wave = threadIdx.x >> 6;
  const int lane = threadIdx.x & 63;
  const int grow = blockIdx.x * 8 + wave;      // global flat q-row
  const int b    = grow >> 11;
  float* msc = ssc[wave];
  int*   mix = sidx[wave];

  int cnt_p = 0;
  if (lane < 32) cnt_p = counts[(size_t)grow * 32 + lane];
  const float2* myslots = cand + ((size_t)grow * 32 + lane) * CAP;

  // pass 1: global row max over candidates
  float mv = -3e38f;
  for (int k = 0; k < cnt_p; ++k) mv = fmaxf(mv, myslots[k].x);
  #pragma unroll
  for (int off = 32; off > 0; off >>= 1) mv = fmaxf(mv, __shfl_xor(mv, off));
  const bool dead = (mv <= -1e29f);   // fully-masked row -> uniform softmax

  float total_g = 0.f;
  f32x4 oacc[4];
  #pragma unroll
  for (int j = 0; j < 4; ++j) oacc[j] = (f32x4){0.f, 0.f, 0.f, 0.f};
  const float* vbase = values + (size_t)b * SEQ * DIM;

  if (!dead) {
    const float thresh = mv - CAND_THRESH;
    // pass 2: filter count + Z partial
    int f = 0; float zp = 0.f;
    for (int k = 0; k < cnt_p; ++k) {
      float s = myslots[k].x;
      if (s > thresh) { ++f; zp += __expf(s - mv); }
    }
    // prefix over 64 lanes for deterministic compaction order
    int incl = f;
    #pragma unroll
    for (int off = 1; off < 64; off <<= 1) {
      int t = __shfl_up(incl, off);
      if (lane >= off) incl += t;
    }
    const int base = incl - f;
    const int F = __shfl(incl, 63);
    #pragma unroll
    for (int off = 32; off > 0; off >>= 1) zp += __shfl_xor(zp, off);
    const float Z = zp;
    // compact filtered candidates to LDS (order: (pair, slot))
    int w = 0;
    for (int k = 0; k < cnt_p; ++k) {
      float2 cv = myslots[k];
      if (cv.x > thresh) {
        int p = base + w;
        if (p < 128) { msc[p] = cv.x; mix[p] = __float_as_int(cv.y); }
        ++w;
      }
    }
    asm volatile("s_waitcnt lgkmcnt(0)" ::: "memory");

    if (F <= TOPK) {
      // common path: filtered set == significant top-k members
      for (int c = 0; c < F; ++c) {
        float g = expm1f(__expf(msc[c] - mv) / Z);
        total_g += g;
        const float* vrow = vbase + (size_t)mix[c] * DIM;
        #pragma unroll
        for (int j = 0; j < 4; ++j) {
          f32x4 v = *(const f32x4*)(vrow + j * 256 + lane * 4);
          #pragma unroll
          for (int e = 0; e < 4; ++e) oacc[j][e] = fmaf(g, v[e], oacc[j][e]);
        }
      }
    } else {
      // rare path: exact top-64 by (score desc, idx asc) from the list
      const int nlist = F < 128 ? F : 128;
      for (int itk = 0; itk < TOPK; ++itk) {
        float bv = -3e38f; int bi = 1 << 30; int bsl = -1;
        #pragma unroll
        for (int h = 0; h < 2; ++h) {
          int sl = lane + h * 64;
          if (sl < nlist) {
            float v = msc[sl]; int id = mix[sl];
            if (v > bv || (v == bv && id < bi)) { bv = v; bi = id; bsl = sl; }
          }
        }
        #pragma unroll
        for (int off = 32; off > 0; off >>= 1) {
          float ov = __shfl_xor(bv, off);
          int   oi = __shfl_xor(bi, off);
          int   os = __shfl_xor(bsl, off);
          if (ov > bv || (ov == bv && oi < bi)) { bv = ov; bi = oi; bsl = os; }
        }
        if (bv <= -1e29f) break;
        float g = expm1f(__expf(bv - mv) / Z);
        total_g += g;
        const float* vrow = vbase + (size_t)bi * DIM;
        #pragma unroll
        for (int j = 0; j < 4; ++j) {
          f32x4 v = *(const f32x4*)(vrow + j * 256 + lane * 4);
          #pragma unroll
          for (int e = 0; e < 4; ++e) oacc[j][e] = fmaf(g, v[e], oacc[j][e]);
        }
        if (lane == 0) msc[bsl] = -3e38f;
        asm volatile("s_waitcnt lgkmcnt(0)" ::: "memory");
      }
    }
  }

  // out = (colsum + sum g*v) / (2048 + sum g)
  const float inv = 1.0f / (2048.0f + total_g);
  const float* cs = colsum + (size_t)b * DIM;
  float* orow = out + (size_t)grow * DIM;
  #pragma unroll
  for (int j = 0; j < 4; ++j) {
    f32x4 c = *(const f32x4*)(cs + j * 256 + lane * 4);
    f32x4 o;
    #pragma unroll
    for (int e = 0; e < 4; ++e) o[e] = (c[e] + oacc[j][e]) * inv;
    *(f32x4*)(orow + j * 256 + lane * 4) = o;
  }
}

extern "C" void kernel_launch(void* const* d_in, const int* in_sizes, int n_in,
                              void* d_out, int out_size, void* d_ws, size_t ws_size,
                              hipStream_t stream) {
  const float* queries = (const float*)d_in[0];
  const float* keys    = (const float*)d_in[1];
  const float* values  = (const float*)d_in[2];
  const int*   mask    = (const int*)d_in[3];
  const float* W       = (const float*)d_in[4];
  float* out = (float*)d_out;

  // ws layout (bytes), total ~192.3 MB (same proven footprint):
  //   [0, 112M)    cand float2[16384][32][28]
  //       q16 aliases [0, 32M)   (dead before gemm256_scores)
  //       w16 aliases [32M, 34M) (dead before gemm256_scores)
  //   [112M, 114M) counts int[16384][32]
  //   [114M, 118M) maskbits u64[16384][32]
  //   [128M, 160M) qp16 f16 [16384][1024]
  //   [160M, 192M) k16  f16 [8][2048][1024]
  //   [192M, ...)  colsum f32 8192 | partial f32 65536
  char* base = (char*)d_ws;
  float2* cand   = (float2*)base;
  f16*   q16     = (f16*)base;
  f16*   w16     = (f16*)(base + (size_t)32 * 1024 * 1024);
  int*   counts  = (int*)(base + (size_t)112 * 1024 * 1024);
  unsigned long long* maskbits =
      (unsigned long long*)(base + (size_t)114 * 1024 * 1024);
  f16*   qp16    = (f16*)(base + (size_t)128 * 1024 * 1024);
  f16*   k16     = (f16*)(base + (size_t)160 * 1024 * 1024);
  float* colsum  = (float*)(base + (size_t)192 * 1024 * 1024);
  float* partial = colsum + 8192;

  pack_mask_kernel<<<2048, 256, 0, stream>>>((const int4*)mask, maskbits);
  colsum_partial_kernel<<<256, 256, 0, stream>>>(values, partial);
  colsum_reduce_kernel<<<32, 256, 0, stream>>>(partial, colsum);
  cvt_f32_to_f16<<<16384, 256, 0, stream>>>(queries, q16, 16384 * 1024);
  cvt_f32_to_f16<<<1024, 256, 0, stream>>>(W, w16, 1024 * 1024);
  gemm256_qproj<<<256, 512, 0, stream>>>(q16, w16, qp16);
  cvt_f32_to_f16<<<16384, 256, 0, stream>>>(keys, k16, 16384 * 1024);
  gemm256_scores<<<512, 512, 0, stream>>>(qp16, k16, maskbits, cand, counts);
  topk_kernel<<<2048, 512, 0, stream>>>(cand, counts, values, colsum, out);
}